// Round 5
// baseline (271.877 us; speedup 1.0000x reference)
//
#include <hip/hip_runtime.h>
#include <hip/hip_bf16.h>
#include <stdint.h>

// B=2, T=2048, D=1024, H=16, hd=64.
// R10: attn cross-tile software pipeline (T15) -- V fragments captured to
// registers (vfp) each tile; PV(t-1) executes between S-mfma(t) and exp(t)
// as pure-register MFMA, filling the S latency shadow. pw double-buffered
// (pwA/pwB), loop hand-unrolled x2, first/last tiles peeled. Single vfp set
// (PV consumes before VFLOAD refills). Everything else identical to R9.

typedef unsigned short u16;
typedef short bf16x8 __attribute__((ext_vector_type(8)));
typedef float f32x4  __attribute__((ext_vector_type(4)));
typedef float f32x16 __attribute__((ext_vector_type(16)));

#if defined(__has_builtin) && __has_builtin(__builtin_amdgcn_exp2f)
#define EXP2F(x) __builtin_amdgcn_exp2f(x)
#else
#define EXP2F(x) exp2f(x)
#endif

__device__ __forceinline__ u16 f2b(float f) {           // fp32 -> bf16 RNE
  uint32_t u = __float_as_uint(f);
  u += 0x7fffu + ((u >> 16) & 1u);
  return (u16)(u >> 16);
}
__device__ __forceinline__ uint32_t pkbf(float a, float b) {  // v_cvt_pk_bf16_f32
  __hip_bfloat162 h = __float22bfloat162_rn(make_float2(a, b));
  union { __hip_bfloat162 h2; uint32_t u; } cv; cv.h2 = h;
  return cv.u;
}

// async global->LDS DMA, 16B per lane. LDS dest must be uniform-base + lane*16.
__device__ __forceinline__ void gl2lds16(const void* g, void* l) {
  __builtin_amdgcn_global_load_lds(
      (const __attribute__((address_space(1))) unsigned int*)g,
      (__attribute__((address_space(3))) unsigned int*)l, 16, 0, 0);
}

// ---------------------------------------------------------------- dtype sniff
__global__ void sniff_kernel(const u16* x, int* flag) {
  __shared__ int cnt;
  if (threadIdx.x == 0) cnt = 0;
  __syncthreads();
  int c = 0;
  for (int i = threadIdx.x; i < 4096; i += 256) {
    float a = fabsf(__uint_as_float(((uint32_t)x[2*i]) << 16));
    if (a > 1e-3f && a < 100.f) c++;
  }
  atomicAdd(&cnt, c);
  __syncthreads();
  if (threadIdx.x == 0) *flag = (cnt > 2048) ? 1 : 0;
}

// ------------------------------------------------- 64x64 transpose helper
__device__ __forceinline__ void tr_tile(const void* src, u16* dst, int Kd, int N,
                                        int n0, int k0, int isb, u16* Lt, int tid)
{
  const int r = tid >> 2, cseg = (tid & 3) << 4;
  u16 t[16];
  if (isb) {
    const u16* s = (const u16*)src + (size_t)(k0 + r) * N + n0 + cseg;
    *(uint4*)&t[0] = *(const uint4*)s;
    *(uint4*)&t[8] = *(const uint4*)(s + 8);
  } else {
    const float* s = (const float*)src + (size_t)(k0 + r) * N + n0 + cseg;
    #pragma unroll
    for (int j = 0; j < 4; j++) {
      float4 v = *(const float4*)(s + j * 4);
      t[j*4+0] = f2b(v.x); t[j*4+1] = f2b(v.y); t[j*4+2] = f2b(v.z); t[j*4+3] = f2b(v.w);
    }
  }
  #pragma unroll
  for (int j = 0; j < 16; j++) Lt[(cseg + j) * 72 + r] = t[j];
  __syncthreads();
  const int n = tid >> 2, kseg = (tid & 3) << 4;
  uint4 u0 = *(const uint4*)&Lt[n * 72 + kseg];
  uint4 u1 = *(const uint4*)&Lt[n * 72 + kseg + 8];
  u16* d = dst + (size_t)(n0 + n) * Kd + k0 + kseg;
  *(uint4*)d = u0;
  *(uint4*)(d + 8) = u1;
}

// ------------------------------------------------- fused prep
// blocks [0,2048): x->bf16 ; [2048,2816): Wqkv^T ; [2816,3072): Wout^T ;
// [3072,3328): RoPE table CS[t*32+f] = {cos,sin}
__global__ __launch_bounds__(256) void prep_kernel(
    const void* __restrict__ x, const void* __restrict__ wqkv,
    const void* __restrict__ wout, const int* __restrict__ flag,
    u16* __restrict__ Xb, u16* __restrict__ Wqkvt, u16* __restrict__ Woutt,
    float2* __restrict__ CS)
{
  __shared__ u16 Lt[64 * 72];
  const int isb = *flag;
  const int bid = blockIdx.x, tid = threadIdx.x;
  if (bid < 2048) {
    const size_t i = ((size_t)bid * 256 + tid) * 8;
    if (isb) {
      *(uint4*)&Xb[i] = *(const uint4*)((const u16*)x + i);
    } else {
      const float* s = (const float*)x + i;
      float4 a = *(const float4*)s, b = *(const float4*)(s + 4);
      uint4 p;
      p.x = pkbf(a.x, a.y); p.y = pkbf(a.z, a.w);
      p.z = pkbf(b.x, b.y); p.w = pkbf(b.z, b.w);
      *(uint4*)&Xb[i] = p;
    }
  } else if (bid < 2816) {
    const int b = bid - 2048;
    tr_tile(wqkv, Wqkvt, 1024, 3072, (b % 48) * 64, (b / 48) * 64, isb, Lt, tid);
  } else if (bid < 3072) {
    const int b = bid - 2816;
    tr_tile(wout, Woutt, 1024, 1024, (b % 16) * 64, (b / 16) * 64, isb, Lt, tid);
  } else {
    const int idx = (bid - 3072) * 256 + tid;   // 65536
    const int t = idx >> 5, f = idx & 31;
    float invf = __expf(-(float)f * 0.2878231366242557f);  // ln(1e4)/32
    float th = (float)t * invf;
    float sn, cs;
    sincosf(th, &sn, &cs);
    CS[idx] = make_float2(cs, sn);
  }
}

// ------------------------------------------------- QKV GEMM (NT, bf16) + RoPE
// Q/K waves accumulate C^T (mfma(bf,af)): lane holds 4 consecutive d at fixed
// t -> in-lane RoPE, float4 CS loads, packed uint2 stores. V waves keep the
// original orientation; V's t-index is stored sigma4-permuted (swap bits 2<->3
// of t&15) to match the attn PV k-order.
__global__ __launch_bounds__(256) void qkv_kernel(
    const u16* __restrict__ Xb, const u16* __restrict__ Wt,
    const float2* __restrict__ CS,
    u16* __restrict__ Q, u16* __restrict__ K, u16* __restrict__ Vt)
{
  __shared__ u16 As[128 * 64];
  __shared__ u16 Bs[128 * 64];
  const int tid = threadIdx.x;
  const int n0 = blockIdx.x * 128;
  const int m0 = blockIdx.y * 128;
  const int w = tid >> 6, l = tid & 63, lr = l & 15, lq = l >> 4;
  const int mrow0 = (w & 1) * 64;
  const int ncol0 = (w >> 1) * 64;
  const int srow = tid >> 3;
  const int gseg = (tid & 7) ^ (srow & 7);

  const int col0 = n0 + ncol0;
  const int sec = col0 >> 10;            // 0=q 1=k 2=v
  const int isv = (sec == 2);
  const int h = (col0 >> 6) & 15;

  f32x4 acc[4][4] = {};

  for (int k0 = 0; k0 < 1024; k0 += 64) {
    __syncthreads();
    #pragma unroll
    for (int rd = 0; rd < 4; rd++) {
      const int row = srow + rd * 32;
      gl2lds16(Xb + (size_t)(m0 + row) * 1024 + k0 + gseg * 8, &As[tid * 8 + rd * 2048]);
      gl2lds16(Wt + (size_t)(n0 + row) * 1024 + k0 + gseg * 8, &Bs[tid * 8 + rd * 2048]);
    }
    __syncthreads();
    #pragma unroll
    for (int kc = 0; kc < 2; kc++) {
      bf16x8 af[4], bf[4];
      #pragma unroll
      for (int i = 0; i < 4; i++) {
        const int seg = ((kc << 2) | lq) ^ (lr & 7);
        af[i] = *(const bf16x8*)&As[(mrow0 + i * 16 + lr) * 64 + seg * 8];
        bf[i] = *(const bf16x8*)&Bs[(ncol0 + i * 16 + lr) * 64 + seg * 8];
      }
      if (isv) {
        #pragma unroll
        for (int mb = 0; mb < 4; mb++)
          #pragma unroll
          for (int nb = 0; nb < 4; nb++)
            acc[mb][nb] = __builtin_amdgcn_mfma_f32_16x16x32_bf16(af[mb], bf[nb], acc[mb][nb], 0, 0, 0);
      } else {
        // transposed: rows = n (d), cols = m (t)
        #pragma unroll
        for (int mb = 0; mb < 4; mb++)
          #pragma unroll
          for (int nb = 0; nb < 4; nb++)
            acc[mb][nb] = __builtin_amdgcn_mfma_f32_16x16x32_bf16(bf[nb], af[mb], acc[mb][nb], 0, 0, 0);
      }
    }
  }

  if (isv) {
    #pragma unroll
    for (int mb = 0; mb < 4; mb++) {
      const int row0 = m0 + mrow0 + mb * 16 + lq * 4;
      const int b = row0 >> 11, t0 = row0 & 2047;
      // sigma4: swap bits 2 and 3 of t (t0 is a multiple of 4):
      const int tp = (t0 & ~12) | ((t0 & 4) << 1) | ((t0 & 8) >> 1);
      #pragma unroll
      for (int nb = 0; nb < 4; nb++) {
        const int d = nb * 16 + lr;
        uint2 uv;
        uv.x = pkbf(acc[mb][nb][0], acc[mb][nb][1]);
        uv.y = pkbf(acc[mb][nb][2], acc[mb][nb][3]);
        *(uint2*)&Vt[(((size_t)b * 16 + h) * 64 + d) * 2048 + tp] = uv;
      }
    }
  } else {
    u16* dst = (sec == 0) ? Q : K;
    const float qscale = 0.125f * 1.44269504f;   // 1/sqrt(hd) * log2(e), q only
    #pragma unroll
    for (int mb = 0; mb < 4; mb++) {
      const int m = m0 + mrow0 + mb * 16 + lr;   // global row = b*2048 + t
      const int b = m >> 11, t = m & 2047;
      const float* csrow = (const float*)(CS + t * 32);
      #pragma unroll
      for (int nb = 0; nb < 4; nb++) {
        const int d = nb * 16 + lq * 4;          // 4 consecutive d, d%4==0
        const int fb = d & 31;                   // pair block stays within 32
        f32x4 c01 = *(const f32x4*)(csrow + 2 * fb);      // {c0,s0,c1,s1}
        f32x4 c23 = *(const f32x4*)(csrow + 2 * fb + 4);  // {c2,s2,c3,s3}
        float v0 = acc[mb][nb][0], v1 = acc[mb][nb][1];
        float v2 = acc[mb][nb][2], v3 = acc[mb][nb][3];
        float r0 = v0 * c01[0] - v1 * c01[1];
        float r1 = fmaf(v1, c01[2], v0 * c01[3]);
        float r2 = v2 * c23[0] - v3 * c23[1];
        float r3 = fmaf(v3, c23[2], v2 * c23[3]);
        if (sec == 0) { r0 *= qscale; r1 *= qscale; r2 *= qscale; r3 *= qscale; }
        uint2 uv;
        uv.x = pkbf(r0, r1);
        uv.y = pkbf(r2, r3);
        *(uint2*)&dst[(((size_t)b * 16 + h) * 2048 + t) * 64 + d] = uv;
      }
    }
  }
}

// ------------------------------------------------- MFMA flash attention (R10)
// Block = 4 waves x 32 q-rows. 32x32x16 MFMA, lane owns one q-row. Cross-tile
// pipeline: vfp (V regs) loaded at end of tile t; PV(t-1) executes between
// S-mfma(t) and exp(t). pwA/pwB double buffer, hand-unrolled x2, peeled ends.
__global__ __launch_bounds__(256, 4) void attn_kernel(
    const u16* __restrict__ Q, const u16* __restrict__ K,
    const u16* __restrict__ Vt, u16* __restrict__ ATT,
    float* __restrict__ Op, float* __restrict__ Ls, int ns)
{
  __shared__ u16 Ks[2][64 * 64];    // 16 KB
  __shared__ u16 Vs[2][64 * 64];    // 16 KB
  const int tid = threadIdx.x;
  const int w = tid >> 6, l = tid & 63;
  const int m5 = l & 31, hi = l >> 5;

  // XCD-bijective swizzle
  const int nwg = 512 * ns;
  const int bid = blockIdx.x;
  const int swz = (bid & 7) * (nwg >> 3) + (bid >> 3);
  const int per_bh = 16 * ns;
  const int bh = swz / per_bh;
  const int rem = swz - bh * per_bh;
  const int sh = rem & (ns - 1);
  const int qt = rem / ns;

  const int slen = 2048 / ns;
  const int sbeg = sh * slen;
  const size_t base = (size_t)bh * (2048 * 64);
  const int qrow0 = qt * 128 + w * 32;
  const int t_own = qrow0 + m5;      // this lane's q-row

  // Q fragments (B-operand: col = m5, k-slot hi*8+j = d kd*16+hi*8+j)
  bf16x8 qf[4];
  #pragma unroll
  for (int kd = 0; kd < 4; kd++)
    qf[kd] = *(const bf16x8*)(Q + base + (size_t)t_own * 64 + kd * 16 + hi * 8);

  f32x16 oa[2] = {};                 // O^T: rows d = db*32 + C-row, col t_own
  float lsum = 0.f;
  uint32_t pwA[16], pwB[16];
  bf16x8 vfp[8];                     // [db*4+sblk], carried across one tile

  const int srow = tid >> 3;

  auto stage = [&](int buf_, int s0) {
    #pragma unroll
    for (int rd = 0; rd < 2; rd++) {
      const int row = srow + rd * 32;
      const int gs = (tid & 7) ^ (row & 7) ^ ((row >> 3) & 3);
      gl2lds16(K + base + (size_t)(s0 + row) * 64 + gs * 8, &Ks[buf_][tid * 8 + rd * 2048]);
      gl2lds16(Vt + base + (size_t)row * 2048 + s0 + gs * 8, &Vs[buf_][tid * 8 + rd * 2048]);
    }
  };

#define KF_S(SB, Z)                                                           \
  {                                                                           \
    const int row_ = (SB) * 32 + m5;                                          \
    const int sw_ = (row_ & 7) ^ ((row_ >> 3) & 3);                           \
    bf16x8 kf_[4];                                                            \
    _Pragma("unroll")                                                         \
    for (int kd = 0; kd < 4; kd++)                                            \
      kf_[kd] = *(const bf16x8*)&Ks[buf][row_ * 64 + ((((kd << 1) | hi) ^ sw_) << 3)]; \
    f32x16 zt_ = {};                                                          \
    __builtin_amdgcn_s_setprio(1);                                            \
    zt_ = __builtin_amdgcn_mfma_f32_32x32x16_bf16(kf_[0], qf[0], zt_, 0, 0, 0); \
    zt_ = __builtin_amdgcn_mfma_f32_32x32x16_bf16(kf_[1], qf[1], zt_, 0, 0, 0); \
    zt_ = __builtin_amdgcn_mfma_f32_32x32x16_bf16(kf_[2], qf[2], zt_, 0, 0, 0); \
    zt_ = __builtin_amdgcn_mfma_f32_32x32x16_bf16(kf_[3], qf[3], zt_, 0, 0, 0); \
    __builtin_amdgcn_s_setprio(0);                                            \
    Z = zt_;                                                                  \
  }

#define EXPPACK(Z, PW, BASE)                                                  \
  {                                                                           \
    float e_[16];                                                             \
    _Pragma("unroll")                                                         \
    for (int r = 0; r < 16; r++) e_[r] = EXP2F((Z)[r]);                       \
    lsum += (((e_[0] + e_[1]) + (e_[2] + e_[3])) + ((e_[4] + e_[5]) + (e_[6] + e_[7]))) \
          + (((e_[8] + e_[9]) + (e_[10] + e_[11])) + ((e_[12] + e_[13]) + (e_[14] + e_[15]))); \
    _Pragma("unroll")                                                         \
    for (int w2 = 0; w2 < 8; w2++) PW[(BASE) + w2] = pkbf(e_[2 * w2], e_[2 * w2 + 1]); \
  }

#define PVHALF(DB, PW)                                                        \
  {                                                                           \
    __builtin_amdgcn_s_setprio(1);                                            \
    _Pragma("unroll")                                                         \
    for (int sblk = 0; sblk < 4; sblk++) {                                    \
      union { uint32_t u[4]; bf16x8 v; } pf_;                                 \
      const int sb_ = sblk >> 1, off_ = (sblk & 1) * 4;                       \
      pf_.u[0] = PW[sb_ * 8 + off_ + 0]; pf_.u[1] = PW[sb_ * 8 + off_ + 1];   \
      pf_.u[2] = PW[sb_ * 8 + off_ + 2]; pf_.u[3] = PW[sb_ * 8 + off_ + 3];   \
      oa[DB] = __builtin_amdgcn_mfma_f32_32x32x16_bf16(vfp[(DB) * 4 + sblk], pf_.v, oa[DB], 0, 0, 0); \
    }                                                                         \
    __builtin_amdgcn_s_setprio(0);                                            \
  }

#define VFLOAD()                                                              \
  {                                                                           \
    _Pragma("unroll")                                                         \
    for (int db_ = 0; db_ < 2; db_++) {                                       \
      const int row_ = db_ * 32 + m5;                                         \
      const int sw_ = (row_ & 7) ^ ((row_ >> 3) & 3);                         \
      _Pragma("unroll")                                                       \
      for (int sblk = 0; sblk < 4; sblk++)                                    \
        vfp[db_ * 4 + sblk] = *(const bf16x8*)&Vs[buf][row_ * 64 + ((((sblk << 1) | hi) ^ sw_) << 3)]; \
    }                                                                         \
  }

  stage(0, sbeg);
  const int nt = slen >> 6;          // 16 (ns=2) or 32 (ns=1), always even
  int buf = 0;
  f32x16 z;

  // ---- t = 0 (peeled: no PV)
  __syncthreads();
  stage(1, sbeg + 64);
  KF_S(0, z); EXPPACK(z, pwA, 0);
  KF_S(1, z); EXPPACK(z, pwA, 8);
  VFLOAD();
  buf = 1;

  // ---- main pairs: t = 1,3,...,nt-3 (odd body reads pwA, even reads pwB)
  #pragma unroll 1
  for (int t = 1; t + 1 < nt; t += 2) {
    // odd body: tile t, PV(t-1) from pwA, write pwB
    __syncthreads();
    stage(buf ^ 1, sbeg + (t + 1) * 64);
    KF_S(0, z);
    PVHALF(0, pwA);
    EXPPACK(z, pwB, 0);
    KF_S(1, z);
    PVHALF(1, pwA);
    EXPPACK(z, pwB, 8);
    VFLOAD();
    buf ^= 1;
    // even body: tile t+1, PV(t) from pwB, write pwA
    __syncthreads();
    stage(buf ^ 1, sbeg + (t + 2) * 64);
    KF_S(0, z);
    PVHALF(0, pwB);
    EXPPACK(z, pwA, 0);
    KF_S(1, z);
    PVHALF(1, pwB);
    EXPPACK(z, pwA, 8);
    VFLOAD();
    buf ^= 1;
  }

  // ---- final t = nt-1 (odd body, no stage), then epilogue PV(nt-1)
  __syncthreads();
  KF_S(0, z);
  PVHALF(0, pwA);
  EXPPACK(z, pwB, 0);
  KF_S(1, z);
  PVHALF(1, pwA);
  EXPPACK(z, pwB, 8);
  VFLOAD();
  PVHALF(0, pwB);
  PVHALF(1, pwB);

#undef KF_S
#undef EXPPACK
#undef PVHALF
#undef VFLOAD

  // reduce row sum across the hi pair (lanes l and l+32 share t_own)
  lsum += __shfl_xor(lsum, 32, 64);

  const int b = bh >> 4, h = bh & 15;
  if (ns == 1) {
    const float inv = 1.f / lsum;
    u16* dst = ATT + ((size_t)(b * 2048 + t_own)) * 1024 + h * 64;
    #pragma unroll
    for (int db = 0; db < 2; db++)
      #pragma unroll
      for (int rq = 0; rq < 4; rq++) {
        const int d0 = db * 32 + rq * 8 + hi * 4;
        uint2 u;
        u.x = pkbf(oa[db][4 * rq + 0] * inv, oa[db][4 * rq + 1] * inv);
        u.y = pkbf(oa[db][4 * rq + 2] * inv, oa[db][4 * rq + 3] * inv);
        *(uint2*)&dst[d0] = u;
      }
  } else {
    float* op = Op + (size_t)sh * (65536ull * 64);
    const size_t row = (size_t)bh * 2048 + t_own;
    #pragma unroll
    for (int db = 0; db < 2; db++)
      #pragma unroll
      for (int rq = 0; rq < 4; rq++) {
        const int d0 = db * 32 + rq * 8 + hi * 4;
        f32x4 v;
        v[0] = oa[db][4 * rq + 0]; v[1] = oa[db][4 * rq + 1];
        v[2] = oa[db][4 * rq + 2]; v[3] = oa[db][4 * rq + 3];
        *(f32x4*)&op[row * 64 + d0] = v;
      }
    if (hi == 0) Ls[(size_t)sh * 65536 + row] = lsum;
  }
}

// ------------------------------------------------- combine s-split partials
__global__ __launch_bounds__(256) void combine_kernel(
    const float* __restrict__ Op, const float* __restrict__ Ls, u16* __restrict__ ATT)
{
  const int idx = blockIdx.x * 256 + threadIdx.x;   // 524288
  const int R = idx >> 3;
  const int c = (idx & 7) * 8;
  const float* p0 = Op + (size_t)R * 64 + c;
  const float* p1 = p0 + 65536ull * 64;
  f32x4 a0 = *(const f32x4*)p0, a1 = *(const f32x4*)(p0 + 4);
  f32x4 b0 = *(const f32x4*)p1, b1 = *(const f32x4*)(p1 + 4);
  const float inv = 1.f / (Ls[R] + Ls[65536 + R]);
  const int bh = R >> 11, trow = R & 2047;
  const int b = bh >> 4, h = bh & 15;
  u16* d = ATT + ((size_t)(b * 2048 + trow)) * 1024 + h * 64 + c;
  uint4 u;
  u.x = pkbf((a0[0] + b0[0]) * inv, (a0[1] + b0[1]) * inv);
  u.y = pkbf((a0[2] + b0[2]) * inv, (a0[3] + b0[3]) * inv);
  u.z = pkbf((a1[0] + b1[0]) * inv, (a1[1] + b1[1]) * inv);
  u.w = pkbf((a1[2] + b1[2]) * inv, (a1[3] + b1[3]) * inv);
  *(uint4*)d = u;
}

// ------------------------------------------------- output projection (NT, bf16)
// Transposed accumulators throughout: lane holds 4 consecutive cols at fixed
// row -> vector stores (f32x4 or packed uint2).
__global__ __launch_bounds__(256) void outproj_kernel(
    const u16* __restrict__ A, const u16* __restrict__ Wt,
    const int* __restrict__ flag, void* __restrict__ outv)
{
  __shared__ u16 As[128 * 64];
  __shared__ u16 Bs[128 * 64];
  const int isb = *flag;
  const int tid = threadIdx.x;
  const int n0 = blockIdx.x * 128;
  const int m0 = blockIdx.y * 128;
  const int w = tid >> 6, l = tid & 63, lr = l & 15, lq = l >> 4;
  const int mrow0 = (w & 1) * 64;
  const int ncol0 = (w >> 1) * 64;
  const int srow = tid >> 3;
  const int gseg = (tid & 7) ^ (srow & 7);

  f32x4 acc[4][4] = {};

  for (int k0 = 0; k0 < 1024; k0 += 64) {
    __syncthreads();
    #pragma unroll
    for (int rd = 0; rd < 4; rd++) {
      const int row = srow + rd * 32;
      gl2lds16(A + (size_t)(m0 + row) * 1024 + k0 + gseg * 8, &As[tid * 8 + rd * 2048]);
      gl2lds16(Wt + (size_t)(n0 + row) * 1024 + k0 + gseg * 8, &Bs[tid * 8 + rd * 2048]);
    }
    __syncthreads();
    #pragma unroll
    for (int kc = 0; kc < 2; kc++) {
      bf16x8 af[4], bf[4];
      #pragma unroll
      for (int i = 0; i < 4; i++) {
        const int seg = ((kc << 2) | lq) ^ (lr & 7);
        af[i] = *(const bf16x8*)&As[(mrow0 + i * 16 + lr) * 64 + seg * 8];
        bf[i] = *(const bf16x8*)&Bs[(ncol0 + i * 16 + lr) * 64 + seg * 8];
      }
      #pragma unroll
      for (int mb = 0; mb < 4; mb++)
        #pragma unroll
        for (int nb = 0; nb < 4; nb++)
          acc[mb][nb] = __builtin_amdgcn_mfma_f32_16x16x32_bf16(bf[nb], af[mb], acc[mb][nb], 0, 0, 0);
    }
  }
  #pragma unroll
  for (int mb = 0; mb < 4; mb++) {
    const int row = m0 + mrow0 + mb * 16 + lr;
    #pragma unroll
    for (int nb = 0; nb < 4; nb++) {
      const int col = n0 + ncol0 + nb * 16 + lq * 4;
      f32x4 v = acc[mb][nb];
      if (isb) {
        uint2 uv;
        uv.x = pkbf(v[0], v[1]);
        uv.y = pkbf(v[2], v[3]);
        *(uint2*)&((u16*)outv)[(size_t)row * 1024 + col] = uv;
      } else {
        *(f32x4*)&((float*)outv)[(size_t)row * 1024 + col] = v;
      }
    }
  }
}

extern "C" void kernel_launch(void* const* d_in, const int* in_sizes, int n_in,
                              void* d_out, int out_size, void* d_ws, size_t ws_size,
                              hipStream_t stream)
{
  const void* x    = d_in[0];
  const void* wqkv = d_in[1];
  const void* wout = d_in[2];
  char* ws = (char*)d_ws;
  const size_t MB = 1024 * 1024;
  int*    flag   = (int*)ws;
  float2* CS     = (float2*)(ws + 1024);            // 512 KB
  u16*    Xb     = (u16*)(ws + 1 * MB);             // 8 MB  (aliased by ATT)
  u16*    ATT    = Xb;
  u16*    Wqkvt  = (u16*)(ws + 9 * MB);             // 6 MB
  u16*    Woutt  = (u16*)(ws + 15 * MB);            // 2 MB
  u16*    Q      = (u16*)(ws + 17 * MB);            // 8 MB
  u16*    K      = (u16*)(ws + 25 * MB);             // 8 MB
  u16*    Vt     = (u16*)(ws + 33 * MB);            // 8 MB
  float*  Op     = (float*)(ws + 41 * MB);          // 32 MB (ns=2)
  float*  Ls     = (float*)(ws + 75 * MB);          // 0.5 MB

  const bool split = ws_size >= 76 * MB;            // deterministic across calls
  const int ns = split ? 2 : 1;

  sniff_kernel<<<1, 256, 0, stream>>>((const u16*)x, flag);
  prep_kernel<<<3328, 256, 0, stream>>>(x, wqkv, wout, flag, Xb, Wqkvt, Woutt, CS);
  qkv_kernel<<<dim3(24, 32), 256, 0, stream>>>(Xb, Wqkvt, CS, Q, K, Vt);
  attn_kernel<<<dim3(512 * ns), 256, 0, stream>>>(Q, K, Vt, ATT, Op, Ls, ns);
  if (split)
    combine_kernel<<<2048, 256, 0, stream>>>(Op, Ls, ATT);
  outproj_kernel<<<dim3(8, 32), 256, 0, stream>>>(ATT, Woutt, flag, d_out);
}

// Round 6
// 210.521 us; speedup vs baseline: 1.2915x; 1.2915x over previous
//
#include <hip/hip_runtime.h>
#include <hip/hip_bf16.h>
#include <stdint.h>

// B=2, T=2048, D=1024, H=16, hd=64.
// R11: attn cross-tile pipeline WITHOUT register V (R10 spilled to scratch:
// WRITE_SIZE 35->238MB). V triple-buffered in LDS (3x8KB; total 40KB, still
// 4 blocks/CU). PV(t-1) executes at the TOP of tile t's body (before S, so
// z is not co-live), reading Vs[(t-1)%3] while stage writes Vs[(t+1)%3].
// Only +16 VGPR vs R9 (second pw buffer). Everything else identical to R9.

typedef unsigned short u16;
typedef short bf16x8 __attribute__((ext_vector_type(8)));
typedef float f32x4  __attribute__((ext_vector_type(4)));
typedef float f32x16 __attribute__((ext_vector_type(16)));

#if defined(__has_builtin) && __has_builtin(__builtin_amdgcn_exp2f)
#define EXP2F(x) __builtin_amdgcn_exp2f(x)
#else
#define EXP2F(x) exp2f(x)
#endif

__device__ __forceinline__ u16 f2b(float f) {           // fp32 -> bf16 RNE
  uint32_t u = __float_as_uint(f);
  u += 0x7fffu + ((u >> 16) & 1u);
  return (u16)(u >> 16);
}
__device__ __forceinline__ uint32_t pkbf(float a, float b) {  // v_cvt_pk_bf16_f32
  __hip_bfloat162 h = __float22bfloat162_rn(make_float2(a, b));
  union { __hip_bfloat162 h2; uint32_t u; } cv; cv.h2 = h;
  return cv.u;
}

// async global->LDS DMA, 16B per lane. LDS dest must be uniform-base + lane*16.
__device__ __forceinline__ void gl2lds16(const void* g, void* l) {
  __builtin_amdgcn_global_load_lds(
      (const __attribute__((address_space(1))) unsigned int*)g,
      (__attribute__((address_space(3))) unsigned int*)l, 16, 0, 0);
}

// ---------------------------------------------------------------- dtype sniff
__global__ void sniff_kernel(const u16* x, int* flag) {
  __shared__ int cnt;
  if (threadIdx.x == 0) cnt = 0;
  __syncthreads();
  int c = 0;
  for (int i = threadIdx.x; i < 4096; i += 256) {
    float a = fabsf(__uint_as_float(((uint32_t)x[2*i]) << 16));
    if (a > 1e-3f && a < 100.f) c++;
  }
  atomicAdd(&cnt, c);
  __syncthreads();
  if (threadIdx.x == 0) *flag = (cnt > 2048) ? 1 : 0;
}

// ------------------------------------------------- 64x64 transpose helper
__device__ __forceinline__ void tr_tile(const void* src, u16* dst, int Kd, int N,
                                        int n0, int k0, int isb, u16* Lt, int tid)
{
  const int r = tid >> 2, cseg = (tid & 3) << 4;
  u16 t[16];
  if (isb) {
    const u16* s = (const u16*)src + (size_t)(k0 + r) * N + n0 + cseg;
    *(uint4*)&t[0] = *(const uint4*)s;
    *(uint4*)&t[8] = *(const uint4*)(s + 8);
  } else {
    const float* s = (const float*)src + (size_t)(k0 + r) * N + n0 + cseg;
    #pragma unroll
    for (int j = 0; j < 4; j++) {
      float4 v = *(const float4*)(s + j * 4);
      t[j*4+0] = f2b(v.x); t[j*4+1] = f2b(v.y); t[j*4+2] = f2b(v.z); t[j*4+3] = f2b(v.w);
    }
  }
  #pragma unroll
  for (int j = 0; j < 16; j++) Lt[(cseg + j) * 72 + r] = t[j];
  __syncthreads();
  const int n = tid >> 2, kseg = (tid & 3) << 4;
  uint4 u0 = *(const uint4*)&Lt[n * 72 + kseg];
  uint4 u1 = *(const uint4*)&Lt[n * 72 + kseg + 8];
  u16* d = dst + (size_t)(n0 + n) * Kd + k0 + kseg;
  *(uint4*)d = u0;
  *(uint4*)(d + 8) = u1;
}

// ------------------------------------------------- fused prep
// blocks [0,2048): x->bf16 ; [2048,2816): Wqkv^T ; [2816,3072): Wout^T ;
// [3072,3328): RoPE table CS[t*32+f] = {cos,sin}
__global__ __launch_bounds__(256) void prep_kernel(
    const void* __restrict__ x, const void* __restrict__ wqkv,
    const void* __restrict__ wout, const int* __restrict__ flag,
    u16* __restrict__ Xb, u16* __restrict__ Wqkvt, u16* __restrict__ Woutt,
    float2* __restrict__ CS)
{
  __shared__ u16 Lt[64 * 72];
  const int isb = *flag;
  const int bid = blockIdx.x, tid = threadIdx.x;
  if (bid < 2048) {
    const size_t i = ((size_t)bid * 256 + tid) * 8;
    if (isb) {
      *(uint4*)&Xb[i] = *(const uint4*)((const u16*)x + i);
    } else {
      const float* s = (const float*)x + i;
      float4 a = *(const float4*)s, b = *(const float4*)(s + 4);
      uint4 p;
      p.x = pkbf(a.x, a.y); p.y = pkbf(a.z, a.w);
      p.z = pkbf(b.x, b.y); p.w = pkbf(b.z, b.w);
      *(uint4*)&Xb[i] = p;
    }
  } else if (bid < 2816) {
    const int b = bid - 2048;
    tr_tile(wqkv, Wqkvt, 1024, 3072, (b % 48) * 64, (b / 48) * 64, isb, Lt, tid);
  } else if (bid < 3072) {
    const int b = bid - 2816;
    tr_tile(wout, Woutt, 1024, 1024, (b % 16) * 64, (b / 16) * 64, isb, Lt, tid);
  } else {
    const int idx = (bid - 3072) * 256 + tid;   // 65536
    const int t = idx >> 5, f = idx & 31;
    float invf = __expf(-(float)f * 0.2878231366242557f);  // ln(1e4)/32
    float th = (float)t * invf;
    float sn, cs;
    sincosf(th, &sn, &cs);
    CS[idx] = make_float2(cs, sn);
  }
}

// ------------------------------------------------- QKV GEMM (NT, bf16) + RoPE
// Q/K waves accumulate C^T (mfma(bf,af)): lane holds 4 consecutive d at fixed
// t -> in-lane RoPE, float4 CS loads, packed uint2 stores. V waves keep the
// original orientation; V's t-index is stored sigma4-permuted (swap bits 2<->3
// of t&15) to match the attn PV k-order.
__global__ __launch_bounds__(256) void qkv_kernel(
    const u16* __restrict__ Xb, const u16* __restrict__ Wt,
    const float2* __restrict__ CS,
    u16* __restrict__ Q, u16* __restrict__ K, u16* __restrict__ Vt)
{
  __shared__ u16 As[128 * 64];
  __shared__ u16 Bs[128 * 64];
  const int tid = threadIdx.x;
  const int n0 = blockIdx.x * 128;
  const int m0 = blockIdx.y * 128;
  const int w = tid >> 6, l = tid & 63, lr = l & 15, lq = l >> 4;
  const int mrow0 = (w & 1) * 64;
  const int ncol0 = (w >> 1) * 64;
  const int srow = tid >> 3;
  const int gseg = (tid & 7) ^ (srow & 7);

  const int col0 = n0 + ncol0;
  const int sec = col0 >> 10;            // 0=q 1=k 2=v
  const int isv = (sec == 2);
  const int h = (col0 >> 6) & 15;

  f32x4 acc[4][4] = {};

  for (int k0 = 0; k0 < 1024; k0 += 64) {
    __syncthreads();
    #pragma unroll
    for (int rd = 0; rd < 4; rd++) {
      const int row = srow + rd * 32;
      gl2lds16(Xb + (size_t)(m0 + row) * 1024 + k0 + gseg * 8, &As[tid * 8 + rd * 2048]);
      gl2lds16(Wt + (size_t)(n0 + row) * 1024 + k0 + gseg * 8, &Bs[tid * 8 + rd * 2048]);
    }
    __syncthreads();
    #pragma unroll
    for (int kc = 0; kc < 2; kc++) {
      bf16x8 af[4], bf[4];
      #pragma unroll
      for (int i = 0; i < 4; i++) {
        const int seg = ((kc << 2) | lq) ^ (lr & 7);
        af[i] = *(const bf16x8*)&As[(mrow0 + i * 16 + lr) * 64 + seg * 8];
        bf[i] = *(const bf16x8*)&Bs[(ncol0 + i * 16 + lr) * 64 + seg * 8];
      }
      if (isv) {
        #pragma unroll
        for (int mb = 0; mb < 4; mb++)
          #pragma unroll
          for (int nb = 0; nb < 4; nb++)
            acc[mb][nb] = __builtin_amdgcn_mfma_f32_16x16x32_bf16(af[mb], bf[nb], acc[mb][nb], 0, 0, 0);
      } else {
        // transposed: rows = n (d), cols = m (t)
        #pragma unroll
        for (int mb = 0; mb < 4; mb++)
          #pragma unroll
          for (int nb = 0; nb < 4; nb++)
            acc[mb][nb] = __builtin_amdgcn_mfma_f32_16x16x32_bf16(bf[nb], af[mb], acc[mb][nb], 0, 0, 0);
      }
    }
  }

  if (isv) {
    #pragma unroll
    for (int mb = 0; mb < 4; mb++) {
      const int row0 = m0 + mrow0 + mb * 16 + lq * 4;
      const int b = row0 >> 11, t0 = row0 & 2047;
      // sigma4: swap bits 2 and 3 of t (t0 is a multiple of 4):
      const int tp = (t0 & ~12) | ((t0 & 4) << 1) | ((t0 & 8) >> 1);
      #pragma unroll
      for (int nb = 0; nb < 4; nb++) {
        const int d = nb * 16 + lr;
        uint2 uv;
        uv.x = pkbf(acc[mb][nb][0], acc[mb][nb][1]);
        uv.y = pkbf(acc[mb][nb][2], acc[mb][nb][3]);
        *(uint2*)&Vt[(((size_t)b * 16 + h) * 64 + d) * 2048 + tp] = uv;
      }
    }
  } else {
    u16* dst = (sec == 0) ? Q : K;
    const float qscale = 0.125f * 1.44269504f;   // 1/sqrt(hd) * log2(e), q only
    #pragma unroll
    for (int mb = 0; mb < 4; mb++) {
      const int m = m0 + mrow0 + mb * 16 + lr;   // global row = b*2048 + t
      const int b = m >> 11, t = m & 2047;
      const float* csrow = (const float*)(CS + t * 32);
      #pragma unroll
      for (int nb = 0; nb < 4; nb++) {
        const int d = nb * 16 + lq * 4;          // 4 consecutive d, d%4==0
        const int fb = d & 31;                   // pair block stays within 32
        f32x4 c01 = *(const f32x4*)(csrow + 2 * fb);      // {c0,s0,c1,s1}
        f32x4 c23 = *(const f32x4*)(csrow + 2 * fb + 4);  // {c2,s2,c3,s3}
        float v0 = acc[mb][nb][0], v1 = acc[mb][nb][1];
        float v2 = acc[mb][nb][2], v3 = acc[mb][nb][3];
        float r0 = v0 * c01[0] - v1 * c01[1];
        float r1 = fmaf(v1, c01[2], v0 * c01[3]);
        float r2 = v2 * c23[0] - v3 * c23[1];
        float r3 = fmaf(v3, c23[2], v2 * c23[3]);
        if (sec == 0) { r0 *= qscale; r1 *= qscale; r2 *= qscale; r3 *= qscale; }
        uint2 uv;
        uv.x = pkbf(r0, r1);
        uv.y = pkbf(r2, r3);
        *(uint2*)&dst[(((size_t)b * 16 + h) * 2048 + t) * 64 + d] = uv;
      }
    }
  }
}

// ------------------------------------------------- MFMA flash attention (R11)
// Block = 4 waves x 32 q-rows. 32x32x16 MFMA, lane owns one q-row (col=l&31).
// V triple-buffered in LDS: V(u) lives in slot u%3. Tile t body:
//   barrier; stage(t+1) -> Ks[(t+1)&1], Vs[(t+1)%3];
//   PV(t-1) from Vs[(t-1)%3] + pw_prev  (independent of tile t -> overlaps S);
//   S(t) = mfma32(K,Q) -> exp -> pack -> pw_cur.
// pw ping-pong (pwA/pwB), hand-unrolled x2, peeled first/last tiles.
__global__ __launch_bounds__(256, 4) void attn_kernel(
    const u16* __restrict__ Q, const u16* __restrict__ K,
    const u16* __restrict__ Vt, u16* __restrict__ ATT,
    float* __restrict__ Op, float* __restrict__ Ls, int ns)
{
  __shared__ u16 Ks[2][64 * 64];    // 16 KB
  __shared__ u16 Vs[3][64 * 64];    // 24 KB
  const int tid = threadIdx.x;
  const int w = tid >> 6, l = tid & 63;
  const int m5 = l & 31, hi = l >> 5;

  // XCD-bijective swizzle
  const int nwg = 512 * ns;
  const int bid = blockIdx.x;
  const int swz = (bid & 7) * (nwg >> 3) + (bid >> 3);
  const int per_bh = 16 * ns;
  const int bh = swz / per_bh;
  const int rem = swz - bh * per_bh;
  const int sh = rem & (ns - 1);
  const int qt = rem / ns;

  const int slen = 2048 / ns;
  const int sbeg = sh * slen;
  const size_t base = (size_t)bh * (2048 * 64);
  const int qrow0 = qt * 128 + w * 32;
  const int t_own = qrow0 + m5;      // this lane's q-row

  // Q fragments (B-operand: col = m5, k-slot hi*8+j = d kd*16+hi*8+j)
  bf16x8 qf[4];
  #pragma unroll
  for (int kd = 0; kd < 4; kd++)
    qf[kd] = *(const bf16x8*)(Q + base + (size_t)t_own * 64 + kd * 16 + hi * 8);

  f32x16 oa[2] = {};                 // O^T: rows d = db*32 + C-row, col t_own
  float lsum = 0.f;
  uint32_t pwA[16], pwB[16];

  const int srow = tid >> 3;

  auto stage = [&](int kb, int vslot, int s0) {
    #pragma unroll
    for (int rd = 0; rd < 2; rd++) {
      const int row = srow + rd * 32;
      const int gs = (tid & 7) ^ (row & 7) ^ ((row >> 3) & 3);
      gl2lds16(K + base + (size_t)(s0 + row) * 64 + gs * 8, &Ks[kb][tid * 8 + rd * 2048]);
      gl2lds16(Vt + base + (size_t)row * 2048 + s0 + gs * 8, &Vs[vslot][tid * 8 + rd * 2048]);
    }
  };

  // S(t): 8 mfma32 from Ks[KB] + exp + pack into PW[0..15]
#define SEXP(KB, PW)                                                          \
  {                                                                           \
    _Pragma("unroll")                                                         \
    for (int sb = 0; sb < 2; sb++) {                                          \
      const int row_ = sb * 32 + m5;                                          \
      const int sw_ = (row_ & 7) ^ ((row_ >> 3) & 3);                         \
      bf16x8 kf_[4];                                                          \
      _Pragma("unroll")                                                       \
      for (int kd = 0; kd < 4; kd++)                                          \
        kf_[kd] = *(const bf16x8*)&Ks[KB][row_ * 64 + ((((kd << 1) | hi) ^ sw_) << 3)]; \
      f32x16 z_ = {};                                                         \
      __builtin_amdgcn_s_setprio(1);                                          \
      z_ = __builtin_amdgcn_mfma_f32_32x32x16_bf16(kf_[0], qf[0], z_, 0, 0, 0); \
      z_ = __builtin_amdgcn_mfma_f32_32x32x16_bf16(kf_[1], qf[1], z_, 0, 0, 0); \
      z_ = __builtin_amdgcn_mfma_f32_32x32x16_bf16(kf_[2], qf[2], z_, 0, 0, 0); \
      z_ = __builtin_amdgcn_mfma_f32_32x32x16_bf16(kf_[3], qf[3], z_, 0, 0, 0); \
      __builtin_amdgcn_s_setprio(0);                                          \
      float e_[16];                                                           \
      _Pragma("unroll")                                                       \
      for (int r = 0; r < 16; r++) e_[r] = EXP2F(z_[r]);                      \
      lsum += (((e_[0] + e_[1]) + (e_[2] + e_[3])) + ((e_[4] + e_[5]) + (e_[6] + e_[7]))) \
            + (((e_[8] + e_[9]) + (e_[10] + e_[11])) + ((e_[12] + e_[13]) + (e_[14] + e_[15]))); \
      _Pragma("unroll")                                                       \
      for (int w2 = 0; w2 < 8; w2++) PW[sb * 8 + w2] = pkbf(e_[2 * w2], e_[2 * w2 + 1]); \
    }                                                                         \
  }

  // PV(u): 8 mfma32, V fragments from Vs[VS], P from PW (prev tile's pack)
#define PVFULL(PW, VS)                                                        \
  {                                                                           \
    _Pragma("unroll")                                                         \
    for (int db_ = 0; db_ < 2; db_++) {                                       \
      const int row_ = db_ * 32 + m5;                                         \
      const int sw_ = (row_ & 7) ^ ((row_ >> 3) & 3);                         \
      bf16x8 vf_[4];                                                          \
      _Pragma("unroll")                                                       \
      for (int sblk = 0; sblk < 4; sblk++)                                    \
        vf_[sblk] = *(const bf16x8*)&Vs[VS][row_ * 64 + ((((sblk << 1) | hi) ^ sw_) << 3)]; \
      __builtin_amdgcn_s_setprio(1);                                          \
      _Pragma("unroll")                                                       \
      for (int sblk = 0; sblk < 4; sblk++) {                                  \
        union { uint32_t u[4]; bf16x8 v; } pf_;                               \
        const int sb_ = sblk >> 1, off_ = (sblk & 1) * 4;                     \
        pf_.u[0] = PW[sb_ * 8 + off_ + 0]; pf_.u[1] = PW[sb_ * 8 + off_ + 1]; \
        pf_.u[2] = PW[sb_ * 8 + off_ + 2]; pf_.u[3] = PW[sb_ * 8 + off_ + 3]; \
        oa[db_] = __builtin_amdgcn_mfma_f32_32x32x16_bf16(vf_[sblk], pf_.v, oa[db_], 0, 0, 0); \
      }                                                                       \
      __builtin_amdgcn_s_setprio(0);                                          \
    }                                                                         \
  }

  stage(0, 0, sbeg);                 // V(0) -> slot 0
  const int nt = slen >> 6;          // 16 (ns=2) or 32 (ns=1), even

  // ---- t = 0 (peeled: no PV). stage V(1) -> slot 1.
  __syncthreads();
  stage(1, 1, sbeg + 64);
  SEXP(0, pwA);

  // slot trackers for tile t (runtime, uniform): p=(t-1)%3, c=t%3, n=(t+1)%3
  int p = 0, c = 1, n = 2;

  // ---- main pairs: tiles t (odd: PV<-pwA, write pwB) and t+1 (even: PV<-pwB)
  #pragma unroll 1
  for (int t = 1; t + 1 < nt; t += 2) {
    // tile t (odd)
    __syncthreads();
    stage((t + 1) & 1, n, sbeg + (t + 1) * 64);
    PVFULL(pwA, p);
    SEXP(t & 1, pwB);
    // tile t+1 (even): stage slot (t+2)%3 == p
    __syncthreads();
    stage(t & 1, p, sbeg + (t + 2) * 64);
    PVFULL(pwB, c);
    SEXP((t + 1) & 1, pwA);
    // rotate for t += 2: (p,c,n) <- (n,p,c)
    const int tmp = p; p = n; n = c; c = tmp;
  }

  // ---- final tile nt-1 (odd): no stage; PV(nt-2) <- pwA, slot p
  __syncthreads();
  PVFULL(pwA, p);
  SEXP(1, pwB);
  // epilogue: PV(nt-1) <- pwB, slot c
  PVFULL(pwB, c);

#undef SEXP
#undef PVFULL

  // reduce row sum across the hi pair (lanes l and l+32 share t_own)
  lsum += __shfl_xor(lsum, 32, 64);

  const int b = bh >> 4, h = bh & 15;
  if (ns == 1) {
    const float inv = 1.f / lsum;
    u16* dst = ATT + ((size_t)(b * 2048 + t_own)) * 1024 + h * 64;
    #pragma unroll
    for (int db = 0; db < 2; db++)
      #pragma unroll
      for (int rq = 0; rq < 4; rq++) {
        const int d0 = db * 32 + rq * 8 + hi * 4;
        uint2 u;
        u.x = pkbf(oa[db][4 * rq + 0] * inv, oa[db][4 * rq + 1] * inv);
        u.y = pkbf(oa[db][4 * rq + 2] * inv, oa[db][4 * rq + 3] * inv);
        *(uint2*)&dst[d0] = u;
      }
  } else {
    float* op = Op + (size_t)sh * (65536ull * 64);
    const size_t row = (size_t)bh * 2048 + t_own;
    #pragma unroll
    for (int db = 0; db < 2; db++)
      #pragma unroll
      for (int rq = 0; rq < 4; rq++) {
        const int d0 = db * 32 + rq * 8 + hi * 4;
        f32x4 v;
        v[0] = oa[db][4 * rq + 0]; v[1] = oa[db][4 * rq + 1];
        v[2] = oa[db][4 * rq + 2]; v[3] = oa[db][4 * rq + 3];
        *(f32x4*)&op[row * 64 + d0] = v;
      }
    if (hi == 0) Ls[(size_t)sh * 65536 + row] = lsum;
  }
}

// ------------------------------------------------- combine s-split partials
__global__ __launch_bounds__(256) void combine_kernel(
    const float* __restrict__ Op, const float* __restrict__ Ls, u16* __restrict__ ATT)
{
  const int idx = blockIdx.x * 256 + threadIdx.x;   // 524288
  const int R = idx >> 3;
  const int c = (idx & 7) * 8;
  const float* p0 = Op + (size_t)R * 64 + c;
  const float* p1 = p0 + 65536ull * 64;
  f32x4 a0 = *(const f32x4*)p0, a1 = *(const f32x4*)(p0 + 4);
  f32x4 b0 = *(const f32x4*)p1, b1 = *(const f32x4*)(p1 + 4);
  const float inv = 1.f / (Ls[R] + Ls[65536 + R]);
  const int bh = R >> 11, trow = R & 2047;
  const int b = bh >> 4, h = bh & 15;
  u16* d = ATT + ((size_t)(b * 2048 + trow)) * 1024 + h * 64 + c;
  uint4 u;
  u.x = pkbf((a0[0] + b0[0]) * inv, (a0[1] + b0[1]) * inv);
  u.y = pkbf((a0[2] + b0[2]) * inv, (a0[3] + b0[3]) * inv);
  u.z = pkbf((a1[0] + b1[0]) * inv, (a1[1] + b1[1]) * inv);
  u.w = pkbf((a1[2] + b1[2]) * inv, (a1[3] + b1[3]) * inv);
  *(uint4*)d = u;
}

// ------------------------------------------------- output projection (NT, bf16)
// Transposed accumulators throughout: lane holds 4 consecutive cols at fixed
// row -> vector stores (f32x4 or packed uint2).
__global__ __launch_bounds__(256) void outproj_kernel(
    const u16* __restrict__ A, const u16* __restrict__ Wt,
    const int* __restrict__ flag, void* __restrict__ outv)
{
  __shared__ u16 As[128 * 64];
  __shared__ u16 Bs[128 * 64];
  const int isb = *flag;
  const int tid = threadIdx.x;
  const int n0 = blockIdx.x * 128;
  const int m0 = blockIdx.y * 128;
  const int w = tid >> 6, l = tid & 63, lr = l & 15, lq = l >> 4;
  const int mrow0 = (w & 1) * 64;
  const int ncol0 = (w >> 1) * 64;
  const int srow = tid >> 3;
  const int gseg = (tid & 7) ^ (srow & 7);

  f32x4 acc[4][4] = {};

  for (int k0 = 0; k0 < 1024; k0 += 64) {
    __syncthreads();
    #pragma unroll
    for (int rd = 0; rd < 4; rd++) {
      const int row = srow + rd * 32;
      gl2lds16(A + (size_t)(m0 + row) * 1024 + k0 + gseg * 8, &As[tid * 8 + rd * 2048]);
      gl2lds16(Wt + (size_t)(n0 + row) * 1024 + k0 + gseg * 8, &Bs[tid * 8 + rd * 2048]);
    }
    __syncthreads();
    #pragma unroll
    for (int kc = 0; kc < 2; kc++) {
      bf16x8 af[4], bf[4];
      #pragma unroll
      for (int i = 0; i < 4; i++) {
        const int seg = ((kc << 2) | lq) ^ (lr & 7);
        af[i] = *(const bf16x8*)&As[(mrow0 + i * 16 + lr) * 64 + seg * 8];
        bf[i] = *(const bf16x8*)&Bs[(ncol0 + i * 16 + lr) * 64 + seg * 8];
      }
      #pragma unroll
      for (int mb = 0; mb < 4; mb++)
        #pragma unroll
        for (int nb = 0; nb < 4; nb++)
          acc[mb][nb] = __builtin_amdgcn_mfma_f32_16x16x32_bf16(bf[nb], af[mb], acc[mb][nb], 0, 0, 0);
    }
  }
  #pragma unroll
  for (int mb = 0; mb < 4; mb++) {
    const int row = m0 + mrow0 + mb * 16 + lr;
    #pragma unroll
    for (int nb = 0; nb < 4; nb++) {
      const int col = n0 + ncol0 + nb * 16 + lq * 4;
      f32x4 v = acc[mb][nb];
      if (isb) {
        uint2 uv;
        uv.x = pkbf(v[0], v[1]);
        uv.y = pkbf(v[2], v[3]);
        *(uint2*)&((u16*)outv)[(size_t)row * 1024 + col] = uv;
      } else {
        *(f32x4*)&((float*)outv)[(size_t)row * 1024 + col] = v;
      }
    }
  }
}

extern "C" void kernel_launch(void* const* d_in, const int* in_sizes, int n_in,
                              void* d_out, int out_size, void* d_ws, size_t ws_size,
                              hipStream_t stream)
{
  const void* x    = d_in[0];
  const void* wqkv = d_in[1];
  const void* wout = d_in[2];
  char* ws = (char*)d_ws;
  const size_t MB = 1024 * 1024;
  int*    flag   = (int*)ws;
  float2* CS     = (float2*)(ws + 1024);            // 512 KB
  u16*    Xb     = (u16*)(ws + 1 * MB);             // 8 MB  (aliased by ATT)
  u16*    ATT    = Xb;
  u16*    Wqkvt  = (u16*)(ws + 9 * MB);             // 6 MB
  u16*    Woutt  = (u16*)(ws + 15 * MB);            // 2 MB
  u16*    Q      = (u16*)(ws + 17 * MB);            // 8 MB
  u16*    K      = (u16*)(ws + 25 * MB);            // 8 MB
  u16*    Vt     = (u16*)(ws + 33 * MB);            // 8 MB
  float*  Op     = (float*)(ws + 41 * MB);          // 32 MB (ns=2)
  float*  Ls     = (float*)(ws + 75 * MB);          // 0.5 MB

  const bool split = ws_size >= 76 * MB;            // deterministic across calls
  const int ns = split ? 2 : 1;

  sniff_kernel<<<1, 256, 0, stream>>>((const u16*)x, flag);
  prep_kernel<<<3328, 256, 0, stream>>>(x, wqkv, wout, flag, Xb, Wqkvt, Woutt, CS);
  qkv_kernel<<<dim3(24, 32), 256, 0, stream>>>(Xb, Wqkvt, CS, Q, K, Vt);
  attn_kernel<<<dim3(512 * ns), 256, 0, stream>>>(Q, K, Vt, ATT, Op, Ls, ns);
  if (split)
    combine_kernel<<<2048, 256, 0, stream>>>(Op, Ls, ATT);
  outproj_kernel<<<dim3(8, 32), 256, 0, stream>>>(ATT, Woutt, flag, d_out);
}

// Round 7
// 197.637 us; speedup vs baseline: 1.3756x; 1.0652x over previous
//
#include <hip/hip_runtime.h>
#include <hip/hip_bf16.h>
#include <stdint.h>

// B=2, T=2048, D=1024, H=16, hd=64.
// R12: in-block s-split attention -- 8-wave blocks (512 thr): waves 0-3 do
// s in [0,1024), waves 4-7 s in [1024,2048) for the SAME 128 q-rows; each
// shard has its own double-buffered K/V LDS (64KB total, 2 blocks/CU = 16
// waves/CU, unchanged). Partials merged through LDS ([r][lane] layout,
// conflict-free) -> combine kernel DELETED, Op/Ls traffic (77MB) gone.
// Tile body = R9's (simplest of the three measured-equal variants).

typedef unsigned short u16;
typedef short bf16x8 __attribute__((ext_vector_type(8)));
typedef float f32x4  __attribute__((ext_vector_type(4)));
typedef float f32x16 __attribute__((ext_vector_type(16)));

#if defined(__has_builtin) && __has_builtin(__builtin_amdgcn_exp2f)
#define EXP2F(x) __builtin_amdgcn_exp2f(x)
#else
#define EXP2F(x) exp2f(x)
#endif

__device__ __forceinline__ u16 f2b(float f) {           // fp32 -> bf16 RNE
  uint32_t u = __float_as_uint(f);
  u += 0x7fffu + ((u >> 16) & 1u);
  return (u16)(u >> 16);
}
__device__ __forceinline__ uint32_t pkbf(float a, float b) {  // v_cvt_pk_bf16_f32
  __hip_bfloat162 h = __float22bfloat162_rn(make_float2(a, b));
  union { __hip_bfloat162 h2; uint32_t u; } cv; cv.h2 = h;
  return cv.u;
}

// async global->LDS DMA, 16B per lane. LDS dest must be uniform-base + lane*16.
__device__ __forceinline__ void gl2lds16(const void* g, void* l) {
  __builtin_amdgcn_global_load_lds(
      (const __attribute__((address_space(1))) unsigned int*)g,
      (__attribute__((address_space(3))) unsigned int*)l, 16, 0, 0);
}

// ---------------------------------------------------------------- dtype sniff
__global__ void sniff_kernel(const u16* x, int* flag) {
  __shared__ int cnt;
  if (threadIdx.x == 0) cnt = 0;
  __syncthreads();
  int c = 0;
  for (int i = threadIdx.x; i < 4096; i += 256) {
    float a = fabsf(__uint_as_float(((uint32_t)x[2*i]) << 16));
    if (a > 1e-3f && a < 100.f) c++;
  }
  atomicAdd(&cnt, c);
  __syncthreads();
  if (threadIdx.x == 0) *flag = (cnt > 2048) ? 1 : 0;
}

// ------------------------------------------------- 64x64 transpose helper
__device__ __forceinline__ void tr_tile(const void* src, u16* dst, int Kd, int N,
                                        int n0, int k0, int isb, u16* Lt, int tid)
{
  const int r = tid >> 2, cseg = (tid & 3) << 4;
  u16 t[16];
  if (isb) {
    const u16* s = (const u16*)src + (size_t)(k0 + r) * N + n0 + cseg;
    *(uint4*)&t[0] = *(const uint4*)s;
    *(uint4*)&t[8] = *(const uint4*)(s + 8);
  } else {
    const float* s = (const float*)src + (size_t)(k0 + r) * N + n0 + cseg;
    #pragma unroll
    for (int j = 0; j < 4; j++) {
      float4 v = *(const float4*)(s + j * 4);
      t[j*4+0] = f2b(v.x); t[j*4+1] = f2b(v.y); t[j*4+2] = f2b(v.z); t[j*4+3] = f2b(v.w);
    }
  }
  #pragma unroll
  for (int j = 0; j < 16; j++) Lt[(cseg + j) * 72 + r] = t[j];
  __syncthreads();
  const int n = tid >> 2, kseg = (tid & 3) << 4;
  uint4 u0 = *(const uint4*)&Lt[n * 72 + kseg];
  uint4 u1 = *(const uint4*)&Lt[n * 72 + kseg + 8];
  u16* d = dst + (size_t)(n0 + n) * Kd + k0 + kseg;
  *(uint4*)d = u0;
  *(uint4*)(d + 8) = u1;
}

// ------------------------------------------------- fused prep
// blocks [0,2048): x->bf16 ; [2048,2816): Wqkv^T ; [2816,3072): Wout^T ;
// [3072,3328): RoPE table CS[t*32+f] = {cos,sin}
__global__ __launch_bounds__(256) void prep_kernel(
    const void* __restrict__ x, const void* __restrict__ wqkv,
    const void* __restrict__ wout, const int* __restrict__ flag,
    u16* __restrict__ Xb, u16* __restrict__ Wqkvt, u16* __restrict__ Woutt,
    float2* __restrict__ CS)
{
  __shared__ u16 Lt[64 * 72];
  const int isb = *flag;
  const int bid = blockIdx.x, tid = threadIdx.x;
  if (bid < 2048) {
    const size_t i = ((size_t)bid * 256 + tid) * 8;
    if (isb) {
      *(uint4*)&Xb[i] = *(const uint4*)((const u16*)x + i);
    } else {
      const float* s = (const float*)x + i;
      float4 a = *(const float4*)s, b = *(const float4*)(s + 4);
      uint4 p;
      p.x = pkbf(a.x, a.y); p.y = pkbf(a.z, a.w);
      p.z = pkbf(b.x, b.y); p.w = pkbf(b.z, b.w);
      *(uint4*)&Xb[i] = p;
    }
  } else if (bid < 2816) {
    const int b = bid - 2048;
    tr_tile(wqkv, Wqkvt, 1024, 3072, (b % 48) * 64, (b / 48) * 64, isb, Lt, tid);
  } else if (bid < 3072) {
    const int b = bid - 2816;
    tr_tile(wout, Woutt, 1024, 1024, (b % 16) * 64, (b / 16) * 64, isb, Lt, tid);
  } else {
    const int idx = (bid - 3072) * 256 + tid;   // 65536
    const int t = idx >> 5, f = idx & 31;
    float invf = __expf(-(float)f * 0.2878231366242557f);  // ln(1e4)/32
    float th = (float)t * invf;
    float sn, cs;
    sincosf(th, &sn, &cs);
    CS[idx] = make_float2(cs, sn);
  }
}

// ------------------------------------------------- QKV GEMM (NT, bf16) + RoPE
// Q/K waves accumulate C^T (mfma(bf,af)): lane holds 4 consecutive d at fixed
// t -> in-lane RoPE, float4 CS loads, packed uint2 stores. V waves keep the
// original orientation; V's t-index is stored sigma4-permuted (swap bits 2<->3
// of t&15) to match the attn PV k-order.
__global__ __launch_bounds__(256) void qkv_kernel(
    const u16* __restrict__ Xb, const u16* __restrict__ Wt,
    const float2* __restrict__ CS,
    u16* __restrict__ Q, u16* __restrict__ K, u16* __restrict__ Vt)
{
  __shared__ u16 As[128 * 64];
  __shared__ u16 Bs[128 * 64];
  const int tid = threadIdx.x;
  const int n0 = blockIdx.x * 128;
  const int m0 = blockIdx.y * 128;
  const int w = tid >> 6, l = tid & 63, lr = l & 15, lq = l >> 4;
  const int mrow0 = (w & 1) * 64;
  const int ncol0 = (w >> 1) * 64;
  const int srow = tid >> 3;
  const int gseg = (tid & 7) ^ (srow & 7);

  const int col0 = n0 + ncol0;
  const int sec = col0 >> 10;            // 0=q 1=k 2=v
  const int isv = (sec == 2);
  const int h = (col0 >> 6) & 15;

  f32x4 acc[4][4] = {};

  for (int k0 = 0; k0 < 1024; k0 += 64) {
    __syncthreads();
    #pragma unroll
    for (int rd = 0; rd < 4; rd++) {
      const int row = srow + rd * 32;
      gl2lds16(Xb + (size_t)(m0 + row) * 1024 + k0 + gseg * 8, &As[tid * 8 + rd * 2048]);
      gl2lds16(Wt + (size_t)(n0 + row) * 1024 + k0 + gseg * 8, &Bs[tid * 8 + rd * 2048]);
    }
    __syncthreads();
    #pragma unroll
    for (int kc = 0; kc < 2; kc++) {
      bf16x8 af[4], bf[4];
      #pragma unroll
      for (int i = 0; i < 4; i++) {
        const int seg = ((kc << 2) | lq) ^ (lr & 7);
        af[i] = *(const bf16x8*)&As[(mrow0 + i * 16 + lr) * 64 + seg * 8];
        bf[i] = *(const bf16x8*)&Bs[(ncol0 + i * 16 + lr) * 64 + seg * 8];
      }
      if (isv) {
        #pragma unroll
        for (int mb = 0; mb < 4; mb++)
          #pragma unroll
          for (int nb = 0; nb < 4; nb++)
            acc[mb][nb] = __builtin_amdgcn_mfma_f32_16x16x32_bf16(af[mb], bf[nb], acc[mb][nb], 0, 0, 0);
      } else {
        // transposed: rows = n (d), cols = m (t)
        #pragma unroll
        for (int mb = 0; mb < 4; mb++)
          #pragma unroll
          for (int nb = 0; nb < 4; nb++)
            acc[mb][nb] = __builtin_amdgcn_mfma_f32_16x16x32_bf16(bf[nb], af[mb], acc[mb][nb], 0, 0, 0);
      }
    }
  }

  if (isv) {
    #pragma unroll
    for (int mb = 0; mb < 4; mb++) {
      const int row0 = m0 + mrow0 + mb * 16 + lq * 4;
      const int b = row0 >> 11, t0 = row0 & 2047;
      // sigma4: swap bits 2 and 3 of t (t0 is a multiple of 4):
      const int tp = (t0 & ~12) | ((t0 & 4) << 1) | ((t0 & 8) >> 1);
      #pragma unroll
      for (int nb = 0; nb < 4; nb++) {
        const int d = nb * 16 + lr;
        uint2 uv;
        uv.x = pkbf(acc[mb][nb][0], acc[mb][nb][1]);
        uv.y = pkbf(acc[mb][nb][2], acc[mb][nb][3]);
        *(uint2*)&Vt[(((size_t)b * 16 + h) * 64 + d) * 2048 + tp] = uv;
      }
    }
  } else {
    u16* dst = (sec == 0) ? Q : K;
    const float qscale = 0.125f * 1.44269504f;   // 1/sqrt(hd) * log2(e), q only
    #pragma unroll
    for (int mb = 0; mb < 4; mb++) {
      const int m = m0 + mrow0 + mb * 16 + lr;   // global row = b*2048 + t
      const int b = m >> 11, t = m & 2047;
      const float* csrow = (const float*)(CS + t * 32);
      #pragma unroll
      for (int nb = 0; nb < 4; nb++) {
        const int d = nb * 16 + lq * 4;          // 4 consecutive d, d%4==0
        const int fb = d & 31;                   // pair block stays within 32
        f32x4 c01 = *(const f32x4*)(csrow + 2 * fb);      // {c0,s0,c1,s1}
        f32x4 c23 = *(const f32x4*)(csrow + 2 * fb + 4);  // {c2,s2,c3,s3}
        float v0 = acc[mb][nb][0], v1 = acc[mb][nb][1];
        float v2 = acc[mb][nb][2], v3 = acc[mb][nb][3];
        float r0 = v0 * c01[0] - v1 * c01[1];
        float r1 = fmaf(v1, c01[2], v0 * c01[3]);
        float r2 = v2 * c23[0] - v3 * c23[1];
        float r3 = fmaf(v3, c23[2], v2 * c23[3]);
        if (sec == 0) { r0 *= qscale; r1 *= qscale; r2 *= qscale; r3 *= qscale; }
        uint2 uv;
        uv.x = pkbf(r0, r1);
        uv.y = pkbf(r2, r3);
        *(uint2*)&dst[(((size_t)b * 16 + h) * 2048 + t) * 64 + d] = uv;
      }
    }
  }
}

// ------------------------------------------------- MFMA flash attention (R12)
// Block = 8 waves (512 thr): shard = wave>>2 picks the s-half; subwave ws =
// wave&3 picks 32 q-rows of the block's 128. Each shard double-buffers its
// own K/V (pool 64KB). 32x32x16 MFMA, lane owns one q-row; sigma4-permuted
// Vt makes S^T C-regs the PV B-operand. Partials merged via LDS, written
// directly to ATT -- no Op/Ls, no combine kernel.
__global__ __launch_bounds__(512, 4) void attn_kernel(
    const u16* __restrict__ Q, const u16* __restrict__ K,
    const u16* __restrict__ Vt, u16* __restrict__ ATT)
{
  __shared__ u16 pool[2][2][2][4096];   // [shard][K=0/V=1][buf][64*64] = 64KB
  const int tid = threadIdx.x;          // 0..511
  const int shard = tid >> 8;
  const int t2 = tid & 255;             // tid within shard
  const int ws = (tid >> 6) & 3;        // subwave (q-group)
  const int l = tid & 63;
  const int m5 = l & 31, hi = l >> 5;

  // XCD-bijective swizzle: grid 512 = 32 bh x 16 qt; 64 consecutive work ids
  // (4 bh) per XCD.
  const int bid = blockIdx.x;
  const int swz = (bid & 7) * 64 + (bid >> 3);
  const int bh = swz >> 4;
  const int qt = swz & 15;

  const int sbeg = shard * 1024;        // this shard's s-range
  const size_t base = (size_t)bh * (2048 * 64);
  const int qrow0 = qt * 128 + ws * 32;
  const int t_own = qrow0 + m5;         // this lane's q-row

  // Q fragments (B-operand: col = m5, k-slot hi*8+j = d kd*16+hi*8+j)
  bf16x8 qf[4];
  #pragma unroll
  for (int kd = 0; kd < 4; kd++)
    qf[kd] = *(const bf16x8*)(Q + base + (size_t)t_own * 64 + kd * 16 + hi * 8);

  f32x16 oa[2] = {};                    // O^T partial: rows d = db*32+C-row
  float lsum = 0.f;

  const int srow = t2 >> 3;

  auto stage = [&](int buf, int s0) {
    #pragma unroll
    for (int rd = 0; rd < 2; rd++) {
      const int row = srow + rd * 32;
      const int gs = (t2 & 7) ^ (row & 7) ^ ((row >> 3) & 3);
      gl2lds16(K + base + (size_t)(s0 + row) * 64 + gs * 8,
               &pool[shard][0][buf][t2 * 8 + rd * 2048]);
      gl2lds16(Vt + base + (size_t)row * 2048 + s0 + gs * 8,
               &pool[shard][1][buf][t2 * 8 + rd * 2048]);
    }
  };

  stage(0, sbeg);
  const int nt = 16;

  #pragma unroll 1
  for (int t = 0; t < nt; t++) {
    const int buf = t & 1;
    __syncthreads();                    // drains DMA for buf, fences prev reads
    if (t + 1 < nt) stage(buf ^ 1, sbeg + (t + 1) * 64);
    const u16* Ks = pool[shard][0][buf];
    const u16* Vs = pool[shard][1][buf];

    // ---- S phase: per s-block of 32, kf row = sb*32+m5, d-seg (kd<<1)|hi
    uint32_t pw[2][8];
    #pragma unroll
    for (int sb = 0; sb < 2; sb++) {
      const int row = sb * 32 + m5;
      const int sw = (row & 7) ^ ((row >> 3) & 3);
      bf16x8 kf[4];
      #pragma unroll
      for (int kd = 0; kd < 4; kd++)
        kf[kd] = *(const bf16x8*)&Ks[row * 64 + ((((kd << 1) | hi) ^ sw) << 3)];
      f32x16 z = {};
      __builtin_amdgcn_s_setprio(1);
      z = __builtin_amdgcn_mfma_f32_32x32x16_bf16(kf[0], qf[0], z, 0, 0, 0);
      z = __builtin_amdgcn_mfma_f32_32x32x16_bf16(kf[1], qf[1], z, 0, 0, 0);
      z = __builtin_amdgcn_mfma_f32_32x32x16_bf16(kf[2], qf[2], z, 0, 0, 0);
      z = __builtin_amdgcn_mfma_f32_32x32x16_bf16(kf[3], qf[3], z, 0, 0, 0);
      __builtin_amdgcn_s_setprio(0);
      float e[16];
      #pragma unroll
      for (int r = 0; r < 16; r++) e[r] = EXP2F(z[r]);
      lsum += (((e[0] + e[1]) + (e[2] + e[3])) + ((e[4] + e[5]) + (e[6] + e[7])))
            + (((e[8] + e[9]) + (e[10] + e[11])) + ((e[12] + e[13]) + (e[14] + e[15])));
      #pragma unroll
      for (int w2 = 0; w2 < 8; w2++)
        pw[sb][w2] = pkbf(e[2 * w2], e[2 * w2 + 1]);
    }

    // ---- PV phase: vf row = db*32+m5, t-seg (sblk<<1)|hi (sigma4-linear)
    #pragma unroll
    for (int db = 0; db < 2; db++) {
      const int row = db * 32 + m5;
      const int sw = (row & 7) ^ ((row >> 3) & 3);
      bf16x8 vf[4];
      #pragma unroll
      for (int sblk = 0; sblk < 4; sblk++)
        vf[sblk] = *(const bf16x8*)&Vs[row * 64 + ((((sblk << 1) | hi) ^ sw) << 3)];
      __builtin_amdgcn_s_setprio(1);
      #pragma unroll
      for (int sblk = 0; sblk < 4; sblk++) {
        union { uint32_t u[4]; bf16x8 v; } pf;
        const int sb = sblk >> 1, off = (sblk & 1) * 4;
        pf.u[0] = pw[sb][off + 0]; pf.u[1] = pw[sb][off + 1];
        pf.u[2] = pw[sb][off + 2]; pf.u[3] = pw[sb][off + 3];
        oa[db] = __builtin_amdgcn_mfma_f32_32x32x16_bf16(vf[sblk], pf.v, oa[db], 0, 0, 0);
      }
      __builtin_amdgcn_s_setprio(0);
    }
  }

  // reduce row sum across the hi pair (lanes l and l+32 share t_own)
  lsum += __shfl_xor(lsum, 32, 64);

  // ---- in-block merge: shard 1 dumps partials to LDS, shard 0 combines.
  // Layout mo[(ws*32 + r)*64 + lane] (lane-contiguous -> conflict-free);
  // lsum at float offset 8192 + ws*64 + lane. 33KB < 64KB pool.
  float* mo = (float*)pool;
  __syncthreads();                      // all tile reads done; pool reusable
  if (shard == 1) {
    #pragma unroll
    for (int db = 0; db < 2; db++)
      #pragma unroll
      for (int r = 0; r < 16; r++)
        mo[((ws * 32 + db * 16 + r) << 6) + l] = oa[db][r];
    mo[8192 + ws * 64 + l] = lsum;
  }
  __syncthreads();
  if (shard == 0) {
    const float ls2 = mo[8192 + ws * 64 + l];
    const float inv = 1.f / (lsum + ls2);
    const int b = bh >> 4, h = bh & 15;
    u16* dst = ATT + ((size_t)(b * 2048 + t_own)) * 1024 + h * 64;
    #pragma unroll
    for (int db = 0; db < 2; db++)
      #pragma unroll
      for (int rq = 0; rq < 4; rq++) {
        const int d0 = db * 32 + rq * 8 + hi * 4;
        float s0 = oa[db][4 * rq + 0] + mo[((ws * 32 + db * 16 + 4 * rq + 0) << 6) + l];
        float s1 = oa[db][4 * rq + 1] + mo[((ws * 32 + db * 16 + 4 * rq + 1) << 6) + l];
        float s2 = oa[db][4 * rq + 2] + mo[((ws * 32 + db * 16 + 4 * rq + 2) << 6) + l];
        float s3 = oa[db][4 * rq + 3] + mo[((ws * 32 + db * 16 + 4 * rq + 3) << 6) + l];
        uint2 u;
        u.x = pkbf(s0 * inv, s1 * inv);
        u.y = pkbf(s2 * inv, s3 * inv);
        *(uint2*)&dst[d0] = u;
      }
  }
}

// ------------------------------------------------- output projection (NT, bf16)
// Transposed accumulators throughout: lane holds 4 consecutive cols at fixed
// row -> vector stores (f32x4 or packed uint2).
__global__ __launch_bounds__(256) void outproj_kernel(
    const u16* __restrict__ A, const u16* __restrict__ Wt,
    const int* __restrict__ flag, void* __restrict__ outv)
{
  __shared__ u16 As[128 * 64];
  __shared__ u16 Bs[128 * 64];
  const int isb = *flag;
  const int tid = threadIdx.x;
  const int n0 = blockIdx.x * 128;
  const int m0 = blockIdx.y * 128;
  const int w = tid >> 6, l = tid & 63, lr = l & 15, lq = l >> 4;
  const int mrow0 = (w & 1) * 64;
  const int ncol0 = (w >> 1) * 64;
  const int srow = tid >> 3;
  const int gseg = (tid & 7) ^ (srow & 7);

  f32x4 acc[4][4] = {};

  for (int k0 = 0; k0 < 1024; k0 += 64) {
    __syncthreads();
    #pragma unroll
    for (int rd = 0; rd < 4; rd++) {
      const int row = srow + rd * 32;
      gl2lds16(A + (size_t)(m0 + row) * 1024 + k0 + gseg * 8, &As[tid * 8 + rd * 2048]);
      gl2lds16(Wt + (size_t)(n0 + row) * 1024 + k0 + gseg * 8, &Bs[tid * 8 + rd * 2048]);
    }
    __syncthreads();
    #pragma unroll
    for (int kc = 0; kc < 2; kc++) {
      bf16x8 af[4], bf[4];
      #pragma unroll
      for (int i = 0; i < 4; i++) {
        const int seg = ((kc << 2) | lq) ^ (lr & 7);
        af[i] = *(const bf16x8*)&As[(mrow0 + i * 16 + lr) * 64 + seg * 8];
        bf[i] = *(const bf16x8*)&Bs[(ncol0 + i * 16 + lr) * 64 + seg * 8];
      }
      #pragma unroll
      for (int mb = 0; mb < 4; mb++)
        #pragma unroll
        for (int nb = 0; nb < 4; nb++)
          acc[mb][nb] = __builtin_amdgcn_mfma_f32_16x16x32_bf16(bf[nb], af[mb], acc[mb][nb], 0, 0, 0);
    }
  }
  #pragma unroll
  for (int mb = 0; mb < 4; mb++) {
    const int row = m0 + mrow0 + mb * 16 + lr;
    #pragma unroll
    for (int nb = 0; nb < 4; nb++) {
      const int col = n0 + ncol0 + nb * 16 + lq * 4;
      f32x4 v = acc[mb][nb];
      if (isb) {
        uint2 uv;
        uv.x = pkbf(v[0], v[1]);
        uv.y = pkbf(v[2], v[3]);
        *(uint2*)&((u16*)outv)[(size_t)row * 1024 + col] = uv;
      } else {
        *(f32x4*)&((float*)outv)[(size_t)row * 1024 + col] = v;
      }
    }
  }
}

extern "C" void kernel_launch(void* const* d_in, const int* in_sizes, int n_in,
                              void* d_out, int out_size, void* d_ws, size_t ws_size,
                              hipStream_t stream)
{
  const void* x    = d_in[0];
  const void* wqkv = d_in[1];
  const void* wout = d_in[2];
  char* ws = (char*)d_ws;
  const size_t MB = 1024 * 1024;
  int*    flag   = (int*)ws;
  float2* CS     = (float2*)(ws + 1024);            // 512 KB
  u16*    Xb     = (u16*)(ws + 1 * MB);             // 8 MB  (aliased by ATT)
  u16*    ATT    = Xb;
  u16*    Wqkvt  = (u16*)(ws + 9 * MB);             // 6 MB
  u16*    Woutt  = (u16*)(ws + 15 * MB);            // 2 MB
  u16*    Q      = (u16*)(ws + 17 * MB);            // 8 MB
  u16*    K      = (u16*)(ws + 25 * MB);            // 8 MB
  u16*    Vt     = (u16*)(ws + 33 * MB);            // 8 MB

  sniff_kernel<<<1, 256, 0, stream>>>((const u16*)x, flag);
  prep_kernel<<<3328, 256, 0, stream>>>(x, wqkv, wout, flag, Xb, Wqkvt, Woutt, CS);
  qkv_kernel<<<dim3(24, 32), 256, 0, stream>>>(Xb, Wqkvt, CS, Q, K, Vt);
  attn_kernel<<<dim3(512), 512, 0, stream>>>(Q, K, Vt, ATT);
  outproj_kernel<<<dim3(8, 32), 256, 0, stream>>>(ATT, Woutt, flag, d_out);
}